// Round 9
// baseline (462.724 us; speedup 1.0000x reference)
//
#include <hip/hip_runtime.h>
#include <cstdint>
#include <cstddef>

#define BETA 5.5f
#define ALPHA 0.5f

constexpr int D   = 512;     // feature dim
constexpr int NB  = 4096;    // queries
constexpr int NK  = 16384;   // keys
constexpr int BQ  = 32;      // query tile per block
constexpr int BN  = 64;      // key chunk
constexpr int NSPLIT = 8;    // nsplit == XCD id under round-robin -> ~4MB L2 slice
constexpr int NRANGE = NK / NSPLIT;   // 2048
constexpr int CHUNKS = NRANGE / BN;   // 32
constexpr int KROW = D + 8;           // norm_k LDS row pad
constexpr int PROW = BN + 8;          // padded P row: 72
// KnF fragment-major: elem off = chunkg*32768 + ntile*8192 + kh*4096 + ks*512 + lane*8
//   (chunkg = global 64-key chunk, ntile = 16-key group 0..3, kh = D-half, ks = 32-d step)
constexpr int KFCH = 64 * 512;        // 32768 elems per 64-key chunk

typedef __attribute__((ext_vector_type(8)))  short    short8;
typedef __attribute__((ext_vector_type(4)))  float    floatx4;
typedef __attribute__((ext_vector_type(4)))  uint32_t uint4v;
typedef __attribute__((ext_vector_type(2)))  uint32_t uint2v;

__device__ inline uint32_t f2bf1(float f) {
  union { float f; uint32_t u; } v; v.f = f;
  return (v.u + 0x7FFFu + ((v.u >> 16) & 1u)) >> 16;   // RNE
}
__device__ inline uint32_t pack2(float a, float b) {
  return f2bf1(a) | (f2bf1(b) << 16);
}

// ---------------- normalize Q -> Qn (bf16), and init out = Q ----------------
__global__ void norm_q_kernel(const float* __restrict__ q,
                              float* __restrict__ out,
                              unsigned short* __restrict__ Qn) {
  const int wave = threadIdx.x >> 6, lane = threadIdx.x & 63;
  const int row = blockIdx.x * 4 + wave;
  const float4* qr = (const float4*)(q + (size_t)row * D);
  float4 a = qr[lane * 2];
  float4 b = qr[lane * 2 + 1];
  float ss = a.x*a.x + a.y*a.y + a.z*a.z + a.w*a.w
           + b.x*b.x + b.y*b.y + b.z*b.z + b.w*b.w;
#pragma unroll
  for (int m = 32; m >= 1; m >>= 1) ss += __shfl_xor(ss, m, 64);
  const float sc = 1.0f / fmaxf(sqrtf(ss), 1e-12f);
  float4* orow = (float4*)(out + (size_t)row * D);
  orow[lane * 2]     = a;
  orow[lane * 2 + 1] = b;
  uint4v w;
  w.x = pack2(a.x*sc, a.y*sc); w.y = pack2(a.z*sc, a.w*sc);
  w.z = pack2(b.x*sc, b.y*sc); w.w = pack2(b.z*sc, b.w*sc);
  *(uint4v*)(Qn + (size_t)row * D + lane * 8) = w;
}

// -- normalize K -> KnF (fragment-major for GEMM1-A) + KnT (transposed) ------
__global__ void norm_k_kernel(const float* __restrict__ k,
                              unsigned short* __restrict__ KnF,
                              unsigned short* __restrict__ KnT) {
  __shared__ unsigned short tile[64 * KROW];
  const int wave = threadIdx.x >> 6, lane = threadIdx.x & 63;
  const int l15 = lane & 15, quad = lane >> 4;
  const int n0 = blockIdx.x * 64;
#pragma unroll
  for (int i = 0; i < 4; ++i) {
    const int rl = wave * 4 + i;
    const int n  = n0 + rl;
    const float4* kr = (const float4*)(k + (size_t)n * D);
    float4 a = kr[lane * 2], b = kr[lane * 2 + 1];
    float ss = a.x*a.x + a.y*a.y + a.z*a.z + a.w*a.w
             + b.x*b.x + b.y*b.y + b.z*b.z + b.w*b.w;
#pragma unroll
    for (int m = 32; m >= 1; m >>= 1) ss += __shfl_xor(ss, m, 64);
    const float sc = 1.0f / fmaxf(sqrtf(ss), 1e-12f);
    uint4v w;
    w.x = pack2(a.x*sc, a.y*sc); w.y = pack2(a.z*sc, a.w*sc);
    w.z = pack2(b.x*sc, b.y*sc); w.w = pack2(b.z*sc, b.w*sc);
    *(uint4v*)&tile[rl * KROW + lane * 8] = w;
  }
  __syncthreads();
  // KnT: [d][n]
  {
    const int dsub = threadIdx.x >> 3;        // 0..127
    const int nl   = (threadIdx.x & 7) * 8;   // 0..56
#pragma unroll
    for (int iter = 0; iter < 4; ++iter) {
      const int d = iter * 128 + dsub;
      uint4v w;
      w.x = (uint32_t)tile[(nl+0)*KROW + d] | ((uint32_t)tile[(nl+1)*KROW + d] << 16);
      w.y = (uint32_t)tile[(nl+2)*KROW + d] | ((uint32_t)tile[(nl+3)*KROW + d] << 16);
      w.z = (uint32_t)tile[(nl+4)*KROW + d] | ((uint32_t)tile[(nl+5)*KROW + d] << 16);
      w.w = (uint32_t)tile[(nl+6)*KROW + d] | ((uint32_t)tile[(nl+7)*KROW + d] << 16);
      *(uint4v*)(KnT + (size_t)d * NK + n0 + nl) = w;
    }
  }
  // KnF: A-frag order. wave -> (ntile = w&3, kh = (w>>2)&1, kp = w>>3)
  {
    const int ntile = wave & 3, kh = (wave >> 2) & 1, kp = wave >> 3;
    unsigned short* dst = KnF + (size_t)blockIdx.x * KFCH
                        + ntile * 8192 + kh * 4096 + lane * 8;
#pragma unroll
    for (int i = 0; i < 4; ++i) {
      const int ks = kp * 4 + i;
      uint4v v = *(const uint4v*)&tile[(ntile*16 + l15) * KROW
                                       + kh*256 + ks*32 + quad*8];
      *(uint4v*)(dst + ks * 512) = v;
    }
  }
}

// ---------------- fused: S = Qn Kn^T chunk, P = exp, O += P Kn --------------
// NO K_lds: GEMM1-A streams from KnF (coalesced, L2-resident), per-wave vmcnt.
// LDS = P-dbuf + Sred only (17.4 KB). kh D-split keeps regs small -> 2 blk/CU
// (4 waves/SIMD). Barriers only order tiny LDS ops (nothing big drains there).
__global__ __launch_bounds__(512, 4) void fused_kernel(
    const unsigned short* __restrict__ Qn,
    const unsigned short* __restrict__ KnF,
    const unsigned short* __restrict__ KnT,
    float* __restrict__ out) {
  __shared__ unsigned short P_lds[2][BQ * PROW];   // 9216 B
  __shared__ float Sred[8][16 * 16];               // 8192 B   total 17.4 KB

  const int tid  = threadIdx.x;
  const int wave = tid >> 6, lane = tid & 63;
  const int l15  = lane & 15, quad = lane >> 4;
  const int nsplit = blockIdx.x & (NSPLIT - 1);
  const int qidx   = blockIdx.x >> 3;           // 0..127
  const int q0     = qidx * BQ;
  const int nbase  = nsplit * NRANGE;
  // roles: nh2 -> n-tiles {2nh2, 2nh2+1}; qt -> 16-q group; kh -> D-half
  const int nh2 = wave & 1, qt = (wave >> 1) & 1, kh = wave >> 2;

  // GEMM1 B-frags (Q, this wave's D-half): loaded once (32 VGPR)
  short8 qfB[8];
  {
    const unsigned short* qrow = Qn + (size_t)(q0 + qt*16 + l15) * D
                                 + kh * 256 + quad * 8;
#pragma unroll
    for (int ks = 0; ks < 8; ++ks) qfB[ks] = *(const short8*)(qrow + ks * 32);
  }

  floatx4 oacc[2][4] = {};   // 32q x 64d slice (d cols wave*64..+63)
  short8  ktf[4];            // GEMM2 B-frags, one kb2 half at a time (16 VGPR)

  // per-wave KnF stream base (its 2 n-tiles, its kh half)
  const unsigned short* kfbase = KnF + (size_t)(nsplit * CHUNKS) * KFCH
                               + nh2 * 2 * 8192 + kh * 4096 + lane * 8;
  const unsigned short* ktrow = KnT + (size_t)(wave*64 + l15) * NK + nbase + quad*8;

#pragma unroll 1
  for (int c = 0; c < CHUNKS; ++c) {
    const int cur = c & 1;

    // ---- issue ktf (kb2=0) now; consumed after GEMM1 (latency covered)
#pragma unroll
    for (int td = 0; td < 4; ++td)
      ktf[td] = *(const short8*)(ktrow + (size_t)td*16*NK + c*BN);

    // ---- GEMM1: 2 n-tiles over D-half, A streamed from KnF, B = qfB regs
    floatx4 s0 = {}, s1 = {};
    {
      const unsigned short* ka = kfbase + (size_t)c * KFCH;
#pragma unroll
      for (int ks = 0; ks < 8; ++ks) {
        short8 a0 = *(const short8*)(ka + ks * 512);
        short8 a1 = *(const short8*)(ka + 8192 + ks * 512);
        s0 = __builtin_amdgcn_mfma_f32_16x16x32_bf16(a0, qfB[ks], s0, 0, 0, 0);
        s1 = __builtin_amdgcn_mfma_f32_16x16x32_bf16(a1, qfB[ks], s1, 0, 0, 0);
      }
    }
    if (kh == 1) {   // export partial S (lane-symmetric layout)
      *(float4*)&Sred[(nh2*2 + 0)*2 + qt][lane*4] = *(float4*)&s0;
      *(float4*)&Sred[(nh2*2 + 1)*2 + qt][lane*4] = *(float4*)&s1;
    }
    __syncthreads();   // bar-A: Sred visible

    if (kh == 0) {     // reduce halves, exp, pack, write P (GEMM2-A layout)
      float4 r0 = *(const float4*)&Sred[(nh2*2 + 0)*2 + qt][lane*4];
      float4 r1 = *(const float4*)&Sred[(nh2*2 + 1)*2 + qt][lane*4];
      uint2v w0, w1;
      w0.x = pack2(__expf(BETA*(s0[0]+r0.x-1.f)), __expf(BETA*(s0[1]+r0.y-1.f)));
      w0.y = pack2(__expf(BETA*(s0[2]+r0.z-1.f)), __expf(BETA*(s0[3]+r0.w-1.f)));
      w1.x = pack2(__expf(BETA*(s1[0]+r1.x-1.f)), __expf(BETA*(s1[1]+r1.y-1.f)));
      w1.y = pack2(__expf(BETA*(s1[2]+r1.z-1.f)), __expf(BETA*(s1[3]+r1.w-1.f)));
      const int prow = (qt*16 + l15) * PROW;
      *(uint2v*)&P_lds[cur][prow + (nh2*2 + 0)*16 + quad*4] = w0;
      *(uint2v*)&P_lds[cur][prow + (nh2*2 + 1)*16 + quad*4] = w1;
    }
    __syncthreads();   // bar-B: P(c) visible

    // ---- GEMM2 kb2=0: O += P * ktf
#pragma unroll
    for (int tr = 0; tr < 2; ++tr) {
      short8 pf = *(const short8*)&P_lds[cur][(tr*16 + l15) * PROW + quad*8];
#pragma unroll
      for (int td = 0; td < 4; ++td)
        oacc[tr][td] = __builtin_amdgcn_mfma_f32_16x16x32_bf16(
            pf, ktf[td], oacc[tr][td], 0, 0, 0);
    }
    // ---- ktf (kb2=1), then GEMM2 kb2=1
#pragma unroll
    for (int td = 0; td < 4; ++td)
      ktf[td] = *(const short8*)(ktrow + (size_t)td*16*NK + c*BN + 32);
#pragma unroll
    for (int tr = 0; tr < 2; ++tr) {
      short8 pf = *(const short8*)&P_lds[cur][(tr*16 + l15) * PROW + 32 + quad*8];
#pragma unroll
      for (int td = 0; td < 4; ++td)
        oacc[tr][td] = __builtin_amdgcn_mfma_f32_16x16x32_bf16(
            pf, ktf[td], oacc[tr][td], 0, 0, 0);
    }
  }

  // ---- epilogue: out += ALPHA * O (out pre-init to Q; atomics L2-coalesce)
#pragma unroll
  for (int tr = 0; tr < 2; ++tr)
#pragma unroll
    for (int td = 0; td < 4; ++td)
#pragma unroll
      for (int r = 0; r < 4; ++r)
        atomicAdd(out + (size_t)(q0 + tr*16 + quad*4 + r) * D
                      + wave*64 + td*16 + l15,
                  ALPHA * oacc[tr][td][r]);
}

extern "C" void kernel_launch(void* const* d_in, const int* in_sizes, int n_in,
                              void* d_out, int out_size, void* d_ws, size_t ws_size,
                              hipStream_t stream) {
  (void)in_sizes; (void)n_in; (void)out_size; (void)ws_size;
  const float* q = (const float*)d_in[0];
  const float* k = (const float*)d_in[1];
  float* out = (float*)d_out;
  unsigned short* Qn  = (unsigned short*)d_ws;          //  4 MB
  unsigned short* KnF = Qn + (size_t)NB * D;            // 16 MB
  unsigned short* KnT = KnF + (size_t)NK * D;           // 16 MB  (total 36 MB)

  hipLaunchKernelGGL(norm_q_kernel, dim3(NB / 4),  dim3(256),  0, stream, q, out, Qn);
  hipLaunchKernelGGL(norm_k_kernel, dim3(NK / 64), dim3(1024), 0, stream, k, KnF, KnT);
  hipLaunchKernelGGL(fused_kernel, dim3((NB / BQ) * NSPLIT), dim3(512), 0, stream,
                     Qn, KnF, KnT, out);
}

// Round 10
// 309.962 us; speedup vs baseline: 1.4928x; 1.4928x over previous
//
#include <hip/hip_runtime.h>
#include <cstdint>
#include <cstddef>

#define BETA 5.5f
#define ALPHA 0.5f

constexpr int D   = 512;     // feature dim
constexpr int NB  = 4096;    // queries
constexpr int NK  = 16384;   // keys
constexpr int BQ  = 64;      // query tile per block
constexpr int BN  = 64;      // key chunk
constexpr int NSPLIT = 4;
constexpr int NRANGE = NK / NSPLIT;   // 4096
constexpr int CHUNKS = NRANGE / BN;   // 64
constexpr int KROW = D + 8;           // padded LDS row (bf16), 1040 B
constexpr int PROW = BN + 8;          // padded P row: 72

typedef __attribute__((ext_vector_type(8)))  short    short8;
typedef __attribute__((ext_vector_type(4)))  float    floatx4;
typedef __attribute__((ext_vector_type(4)))  uint32_t uint4v;
typedef __attribute__((ext_vector_type(2)))  uint32_t uint2v;

__device__ inline uint32_t f2bf1(float f) {
  union { float f; uint32_t u; } v; v.f = f;
  return (v.u + 0x7FFFu + ((v.u >> 16) & 1u)) >> 16;   // RNE
}
__device__ inline uint32_t pack2(float a, float b) {
  return f2bf1(a) | (f2bf1(b) << 16);
}

__device__ inline void load_lds16(const void* g, void* l) {
  __builtin_amdgcn_global_load_lds(
      (const __attribute__((address_space(1))) uint32_t*)g,
      (__attribute__((address_space(3))) uint32_t*)l, 16, 0, 0);
}

// ---------------- normalize Q -> Qn (bf16), and init out = Q ----------------
__global__ void norm_q_kernel(const float* __restrict__ q,
                              float* __restrict__ out,
                              unsigned short* __restrict__ Qn) {
  const int wave = threadIdx.x >> 6, lane = threadIdx.x & 63;
  const int row = blockIdx.x * 4 + wave;
  const float4* qr = (const float4*)(q + (size_t)row * D);
  float4 a = qr[lane * 2];
  float4 b = qr[lane * 2 + 1];
  float ss = a.x*a.x + a.y*a.y + a.z*a.z + a.w*a.w
           + b.x*b.x + b.y*b.y + b.z*b.z + b.w*b.w;
#pragma unroll
  for (int m = 32; m >= 1; m >>= 1) ss += __shfl_xor(ss, m, 64);
  const float sc = 1.0f / fmaxf(sqrtf(ss), 1e-12f);
  float4* orow = (float4*)(out + (size_t)row * D);
  orow[lane * 2]     = a;
  orow[lane * 2 + 1] = b;
  uint4v w;
  w.x = pack2(a.x*sc, a.y*sc); w.y = pack2(a.z*sc, a.w*sc);
  w.z = pack2(b.x*sc, b.y*sc); w.w = pack2(b.z*sc, b.w*sc);
  *(uint4v*)(Qn + (size_t)row * D + lane * 8) = w;
}

// ------ normalize K -> Kn (bf16 row-major) + KnT (bf16 transposed) ----------
__global__ void norm_k_kernel(const float* __restrict__ k,
                              unsigned short* __restrict__ Kn,
                              unsigned short* __restrict__ KnT) {
  __shared__ unsigned short tile[64 * KROW];
  const int wave = threadIdx.x >> 6, lane = threadIdx.x & 63;
  const int n0 = blockIdx.x * 64;
#pragma unroll
  for (int i = 0; i < 4; ++i) {
    const int rl = wave * 4 + i;
    const int n  = n0 + rl;
    const float4* kr = (const float4*)(k + (size_t)n * D);
    float4 a = kr[lane * 2], b = kr[lane * 2 + 1];
    float ss = a.x*a.x + a.y*a.y + a.z*a.z + a.w*a.w
             + b.x*b.x + b.y*b.y + b.z*b.z + b.w*b.w;
#pragma unroll
    for (int m = 32; m >= 1; m >>= 1) ss += __shfl_xor(ss, m, 64);
    const float sc = 1.0f / fmaxf(sqrtf(ss), 1e-12f);
    uint4v w;
    w.x = pack2(a.x*sc, a.y*sc); w.y = pack2(a.z*sc, a.w*sc);
    w.z = pack2(b.x*sc, b.y*sc); w.w = pack2(b.z*sc, b.w*sc);
    *(uint4v*)(Kn + (size_t)n * D + lane * 8) = w;
    *(uint4v*)&tile[rl * KROW + lane * 8]     = w;
  }
  __syncthreads();
  const int dsub = threadIdx.x >> 3;        // 0..127
  const int nl   = (threadIdx.x & 7) * 8;   // 0..56
#pragma unroll
  for (int iter = 0; iter < 4; ++iter) {
    const int d = iter * 128 + dsub;
    uint4v w;
    w.x = (uint32_t)tile[(nl+0)*KROW + d] | ((uint32_t)tile[(nl+1)*KROW + d] << 16);
    w.y = (uint32_t)tile[(nl+2)*KROW + d] | ((uint32_t)tile[(nl+3)*KROW + d] << 16);
    w.z = (uint32_t)tile[(nl+4)*KROW + d] | ((uint32_t)tile[(nl+5)*KROW + d] << 16);
    w.w = (uint32_t)tile[(nl+6)*KROW + d] | ((uint32_t)tile[(nl+7)*KROW + d] << 16);
    *(uint4v*)(KnT + (size_t)d * NK + n0 + nl) = w;
  }
}

// ---------------- fused: S = Qn Kn^T chunk, P = exp, O += P Kn --------------
// R5 structure + CROSS-BARRIER software pipeline: each inter-barrier region
// contains GEMM2(c) [MFMA-heavy] AND GEMM1(c+1) [LDS-heavy] from the same
// wave, coarse-interleaved, so LDS port and MFMA pipe are both fed (fixes
// the phase convoy that left every pipe <50% busy in R5).
__global__ __launch_bounds__(512, 2) void fused_kernel(
    const unsigned short* __restrict__ Qn,
    const unsigned short* __restrict__ Kn,
    const unsigned short* __restrict__ KnT,
    float* __restrict__ out) {
  __shared__ unsigned short K_lds[2][BN * KROW];   // 2 x 66.5 KB
  __shared__ unsigned short P_lds[2][BQ * PROW];   // 2 x 9.2 KB  (151.5 KB)

  const int tid  = threadIdx.x;
  const int wave = tid >> 6, lane = tid & 63;
  const int l15  = lane & 15, quad = lane >> 4;
  const int nsplit = blockIdx.x & (NSPLIT - 1);
  const int qtile  = blockIdx.x >> 2;           // 0..63
  const int q0     = qtile * BQ;
  const int nbase  = nsplit * NRANGE;
  const int tb = wave & 3, nh = wave >> 2;

  // Q B-fragments in registers: wave's 16-col b-tile, all 512 d (64 VGPR)
  short8 qf[16];
  {
    const unsigned short* qrow = Qn + (size_t)(q0 + tb * 16 + l15) * D + quad * 8;
#pragma unroll
    for (int kb = 0; kb < 16; ++kb) qf[kb] = *(const short8*)(qrow + kb * 32);
  }

  floatx4 oacc[4][4] = {};   // wave's 64x64 O slice
  short8 ktf[2][4];          // KnT B-frags (32 VGPR), single-buffered

  const unsigned short* ktrow = KnT + (size_t)(wave*64 + l15) * NK + nbase + quad*8;

  // helpers as lambdas ---------------------------------------------------
  auto stage = [&](int ch, int buf) {
#pragma unroll
    for (int i = 0; i < 8; ++i) {
      const int row = wave * 8 + i;
      load_lds16(Kn + (size_t)(nbase + ch*BN + row) * D + lane * 8,
                 &K_lds[buf][row * KROW]);
    }
  };
  auto gemm1_half = [&](int buf, int kb0, floatx4& s0, floatx4& s1) {
#pragma unroll
    for (int kb = kb0; kb < kb0 + 8; ++kb) {
      short8 a0 = *(const short8*)&K_lds[buf][(nh*32 +      l15) * KROW + kb*32 + quad*8];
      short8 a1 = *(const short8*)&K_lds[buf][(nh*32 + 16 + l15) * KROW + kb*32 + quad*8];
      s0 = __builtin_amdgcn_mfma_f32_16x16x32_bf16(a0, qf[kb], s0, 0, 0, 0);
      s1 = __builtin_amdgcn_mfma_f32_16x16x32_bf16(a1, qf[kb], s1, 0, 0, 0);
    }
  };
  auto gemm2_half = [&](int buf, int kb2) {
    short8 pf[4];
#pragma unroll
    for (int tr = 0; tr < 4; ++tr)
      pf[tr] = *(const short8*)&P_lds[buf][(tr*16 + l15) * PROW + kb2*32 + quad*8];
#pragma unroll
    for (int td = 0; td < 4; ++td)
#pragma unroll
      for (int tr = 0; tr < 4; ++tr)
        oacc[tr][td] = __builtin_amdgcn_mfma_f32_16x16x32_bf16(
            pf[tr], ktf[kb2][td], oacc[tr][td], 0, 0, 0);
  };
  auto ktf_load = [&](int ch) {
#pragma unroll
    for (int kb2 = 0; kb2 < 2; ++kb2)
#pragma unroll
      for (int td = 0; td < 4; ++td)
        ktf[kb2][td] = *(const short8*)(ktrow + (size_t)td*16*NK + ch*BN + kb2*32);
  };
  auto exp_pw = [&](int buf, const floatx4& s0, const floatx4& s1) {
    const int prow = (tb * 16 + l15) * PROW;
    uint2v w0, w1;
    w0.x = pack2(__expf(BETA * (s0[0] - 1.f)), __expf(BETA * (s0[1] - 1.f)));
    w0.y = pack2(__expf(BETA * (s0[2] - 1.f)), __expf(BETA * (s0[3] - 1.f)));
    w1.x = pack2(__expf(BETA * (s1[0] - 1.f)), __expf(BETA * (s1[1] - 1.f)));
    w1.y = pack2(__expf(BETA * (s1[2] - 1.f)), __expf(BETA * (s1[3] - 1.f)));
    *(uint2v*)&P_lds[buf][prow + (nh*2 + 0) * 16 + quad * 4] = w0;
    *(uint2v*)&P_lds[buf][prow + (nh*2 + 1) * 16 + quad * 4] = w1;
  };
  // ----------------------------------------------------------------------

  // prologue: stage(0); bar; {stage(1); GEMM1(0); exp->P[0]}; bar
  stage(0, 0);
  ktf_load(0);
  __syncthreads();                    // staging(0) drained
  {
    stage(1, 1);
    floatx4 s0 = {}, s1 = {};
    gemm1_half(0, 0, s0, s1);
    gemm1_half(0, 8, s0, s1);
    exp_pw(0, s0, s1);
  }
  __syncthreads();                    // P(0) visible; staging(1) drained

  // steady state: region c = {stage(c+2); GEMM1(c+1); GEMM2(c); ktf(c+1);
  //                           exp->P(c+1)}; barrier
#pragma unroll 1
  for (int c = 0; c + 2 < CHUNKS; ++c) {
    const int cur = c & 1, nxt = cur ^ 1;
    stage(c + 2, cur);                         // K_lds[cur] free (read region c-1)
    floatx4 s0 = {}, s1 = {};
    gemm2_half(cur, 0);                        // GEMM2(c) kb2=0 (P[cur], ktf)
    gemm1_half(nxt, 0, s0, s1);                // GEMM1(c+1) first half
    gemm2_half(cur, 1);                        // GEMM2(c) kb2=1
    gemm1_half(nxt, 8, s0, s1);                // GEMM1(c+1) second half
    ktf_load(c + 1);                           // ktf for GEMM2(c+1)
    exp_pw(nxt, s0, s1);                       // P(c+1) -> P_lds[nxt]
    __syncthreads();
  }
  // tail A: region CHUNKS-2 (no staging): GEMM1(last) + GEMM2(CHUNKS-2)
  {
    const int c = CHUNKS - 2, cur = c & 1, nxt = cur ^ 1;
    floatx4 s0 = {}, s1 = {};
    gemm2_half(cur, 0);
    gemm1_half(nxt, 0, s0, s1);
    gemm2_half(cur, 1);
    gemm1_half(nxt, 8, s0, s1);
    ktf_load(CHUNKS - 1);
    exp_pw(nxt, s0, s1);
    __syncthreads();
  }
  // tail B: GEMM2(CHUNKS-1)
  {
    const int cur = (CHUNKS - 1) & 1;
    gemm2_half(cur, 0);
    gemm2_half(cur, 1);
  }

  // ---- epilogue: out += ALPHA * O (out pre-init to Q; atomics L2-coalesce)
  const int colbase = wave * 64 + l15;
#pragma unroll
  for (int tr = 0; tr < 4; ++tr)
#pragma unroll
    for (int td = 0; td < 4; ++td)
#pragma unroll
      for (int r = 0; r < 4; ++r)
        atomicAdd(out + (size_t)(q0 + tr*16 + quad*4 + r) * D + colbase + td*16,
                  ALPHA * oacc[tr][td][r]);
}

extern "C" void kernel_launch(void* const* d_in, const int* in_sizes, int n_in,
                              void* d_out, int out_size, void* d_ws, size_t ws_size,
                              hipStream_t stream) {
  (void)in_sizes; (void)n_in; (void)out_size; (void)ws_size;
  const float* q = (const float*)d_in[0];
  const float* k = (const float*)d_in[1];
  float* out = (float*)d_out;
  unsigned short* Qn  = (unsigned short*)d_ws;          //  4 MB
  unsigned short* Kn  = Qn + (size_t)NB * D;            // 16 MB
  unsigned short* KnT = Kn + (size_t)NK * D;            // 16 MB  (total 36 MB)

  hipLaunchKernelGGL(norm_q_kernel, dim3(NB / 4),  dim3(256),  0, stream, q, out, Qn);
  hipLaunchKernelGGL(norm_k_kernel, dim3(NK / 64), dim3(1024), 0, stream, k, Kn, KnT);
  hipLaunchKernelGGL(fused_kernel, dim3((NB / BQ) * NSPLIT), dim3(512), 0, stream,
                     Qn, Kn, KnT, out);
}